// Round 1
// 61.747 us; speedup vs baseline: 1.0096x; 1.0096x over previous
//
#include <hip/hip_runtime.h>

typedef _Float16 half8 __attribute__((ext_vector_type(8)));
typedef __fp16   h2 __attribute__((ext_vector_type(2)));
typedef __fp16   h8 __attribute__((ext_vector_type(8)));
typedef float    floatx4 __attribute__((ext_vector_type(4)));
typedef float    fv2 __attribute__((ext_vector_type(2)));
typedef float    fv4 __attribute__((ext_vector_type(4)));

#define STEP  (6.0f / 63.0f)
#define SCAL  1.69864636f     // sqrt(2*log2(e)):  exp(-2 d^2) = 2^(-(S d)^2)

// R14: column-split for 2 blocks/CU (latency hiding).
// 512 blocks = b(16) x rw(16) x colhalf(2); 512 thr = 8 waves.
// Per block: rows rw*4..+3, cols chalf*32..+31 (2 ct-tiles), k split across
// waves (w*128..+128). Same R13 staging + 3-round tree reduction; acc is
// [4][2] (32 VGPR) and per-thread ey exps halve. __launch_bounds__(512,4)
// caps VGPR at 128 so two 8-wave blocks co-reside (LDS 2x64KB=128<=160KB).
__global__ __launch_bounds__(512, 4) void rkhs_fused(
    const float* __restrict__ X,   // (16,1024,2)
    const float* __restrict__ Y,   // (16,1024,8)
    float* __restrict__ out)       // [grid: 8192][Y_grid: 16*4096*9]
{
    __shared__ __align__(16) unsigned char smem[65536];
    float*    sXx   = (float*)smem;              // [1024] S*X.x   (4 KB)
    float*    sXy   = (float*)(smem + 4096);     // [1024] S*X.y   (4 KB)
    _Float16* sEx   = (_Float16*)(smem + 8192);  // [32 s][4 r][32 k] (8 KB)
    floatx4*  spark = (floatx4*)smem;            // reduction alias (32 KB used)
    float*    sfin  = (float*)smem;              // final tile alias

    const int b     = blockIdx.x >> 5;
    const int rw    = (blockIdx.x >> 1) & 15;
    const int chalf = blockIdx.x & 1;
    const int tid = threadIdx.x;
    const int w   = tid >> 6, l = tid & 63, q = l >> 4, n = l & 15;
    const int r0  = rw * 4;

    // ---- issue ALL cold global loads up front (concurrent misses) ----
    const fv4 xv = *(const fv4*)(X + (size_t)b * 2048 + tid * 4); // X[b][2tid..+1]

    float ybf[4][8];
    const bool ldy = (n >= 1 && n <= 8);
    if (ldy) {
#pragma unroll
        for (int ss = 0; ss < 4; ++ss) {
            const float* yp = Y + ((size_t)(b * 1024 + (w * 4 + ss) * 32 + q * 8)) * 8 + (n - 1);
#pragma unroll
            for (int j = 0; j < 8; ++j) ybf[ss][j] = yp[j * 8];
        }
    }

    // grid coords output (b==0, chalf==0 blocks: 16 x 512 floats)
    if (b == 0 && chalf == 0) {
        const int row = r0 + (tid >> 7), rem = tid & 127;
        out[(size_t)rw * 512 + tid] = (rem & 1)
            ? (-3.0f + (float)(rem >> 1) * STEP)
            : (-3.0f + (float)row * STEP);
    }

    // ---- stage S*X into LDS ----
    sXx[2 * tid]     = SCAL * xv[0];
    sXy[2 * tid]     = SCAL * xv[1];
    sXx[2 * tid + 1] = SCAL * xv[2];
    sXy[2 * tid + 1] = SCAL * xv[3];
    __syncthreads();

    // ---- sEx: all 512 threads, 8 exps each, inputs from LDS ----
    {
        const int s = tid >> 4, rr = (tid >> 2) & 3, g = tid & 3;
        const float gS = SCAL * (-3.0f + (float)(r0 + rr) * STEP);
        const float* xp = sXx + s * 32 + g * 8;
        h2 p[4];
#pragma unroll
        for (int hh = 0; hh < 4; ++hh) {
            const float d0 = gS - xp[2 * hh];
            const float d1 = gS - xp[2 * hh + 1];
            p[hh] = __builtin_amdgcn_cvt_pkrtz(
                __builtin_amdgcn_exp2f(-(d0 * d0)),
                __builtin_amdgcn_exp2f(-(d1 * d1)));
        }
        const h8 packed = __builtin_shufflevector(
            __builtin_shufflevector(p[0], p[1], 0, 1, 2, 3),
            __builtin_shufflevector(p[2], p[3], 0, 1, 2, 3),
            0, 1, 2, 3, 4, 5, 6, 7);
        *(half8*)(sEx + (s * 4 + rr) * 32 + g * 8) = __builtin_bit_cast(half8, packed);
    }

    // ---- ybr: register-resident B weights (cvt from hoisted gathers) ----
    half8 ybr[4];
#pragma unroll
    for (int ss = 0; ss < 4; ++ss) {
        half8 h;
        if (n == 0) {
#pragma unroll
            for (int j = 0; j < 8; ++j) h[j] = (_Float16)1.0f;
        } else if (ldy) {
#pragma unroll
            for (int j = 0; j < 8; ++j) h[j] = (_Float16)ybf[ss][j];
        } else {
#pragma unroll
            for (int j = 0; j < 8; ++j) h[j] = (_Float16)0.0f;
        }
        ybr[ss] = h;
    }
    __syncthreads();

    float gSct[2];
#pragma unroll
    for (int ct = 0; ct < 2; ++ct)
        gSct[ct] = SCAL * (-3.0f + (float)(chalf * 32 + ct * 16 + n) * STEP);

    floatx4 acc[4][2];               // [rr][ct]
#pragma unroll
    for (int rr = 0; rr < 4; ++rr)
#pragma unroll
        for (int ct = 0; ct < 2; ++ct) acc[rr][ct] = (floatx4){0.f, 0.f, 0.f, 0.f};

    // ---- main loop: 4 s-steps, no barriers, no staging ----
#pragma unroll
    for (int ss = 0; ss < 4; ++ss) {
        const int s   = w * 4 + ss;
        const int k0q = s * 32 + q * 8;
        const fv4 xa = *(const fv4*)(sXy + k0q);          // broadcast b128
        const fv4 xb = *(const fv4*)(sXy + k0q + 4);
        fv2 xk2[4];
        xk2[0] = __builtin_shufflevector(xa, xa, 0, 1);
        xk2[1] = __builtin_shufflevector(xa, xa, 2, 3);
        xk2[2] = __builtin_shufflevector(xb, xb, 0, 1);
        xk2[3] = __builtin_shufflevector(xb, xb, 2, 3);

        half8 bp[4];
#pragma unroll
        for (int rr = 0; rr < 4; ++rr)
            bp[rr] = (*(const half8*)(sEx + (s * 4 + rr) * 32 + q * 8)) * ybr[ss];

#pragma unroll
        for (int ct = 0; ct < 2; ++ct) {
            const fv2 gS2 = {gSct[ct], gSct[ct]};
            h2 p[4];
#pragma unroll
            for (int hh = 0; hh < 4; ++hh) {
                const fv2 d  = gS2 - xk2[hh];             // v_pk_add_f32
                const fv2 dd = d * d;                     // v_pk_mul_f32
                p[hh] = __builtin_amdgcn_cvt_pkrtz(
                    __builtin_amdgcn_exp2f(-dd[0]),
                    __builtin_amdgcn_exp2f(-dd[1]));
            }
            const h8 packed = __builtin_shufflevector(
                __builtin_shufflevector(p[0], p[1], 0, 1, 2, 3),
                __builtin_shufflevector(p[2], p[3], 0, 1, 2, 3),
                0, 1, 2, 3, 4, 5, 6, 7);
            const half8 ey = __builtin_bit_cast(half8, packed);
#pragma unroll
            for (int rr = 0; rr < 4; ++rr)
                acc[rr][ct] = __builtin_amdgcn_mfma_f32_16x16x32_f16(ey, bp[rr], acc[rr][ct], 0, 0, 0);
        }
    }
    __syncthreads();                 // compute done; LDS free for spark

    // ---- 3-round tree reduction over waves (8 tiles/thread now) ----
#define PARKA(slot)                                                        \
    { _Pragma("unroll") for (int rr = 0; rr < 4; ++rr)                     \
      _Pragma("unroll") for (int ct = 0; ct < 2; ++ct)                     \
          spark[(slot) * 512 + (rr * 2 + ct) * 64 + l] = acc[rr][ct]; }
#define ABSORBA(slot)                                                      \
    { _Pragma("unroll") for (int rr = 0; rr < 4; ++rr)                     \
      _Pragma("unroll") for (int ct = 0; ct < 2; ++ct)                     \
          acc[rr][ct] += spark[(slot) * 512 + (rr * 2 + ct) * 64 + l]; }

    if (w >= 4) PARKA(w - 4)
    __syncthreads();
    if (w < 4)  ABSORBA(w)
    __syncthreads();
    if (w == 2 || w == 3) PARKA(w - 2)
    __syncthreads();
    if (w < 2)  ABSORBA(w)
    __syncthreads();
    if (w == 1) PARKA(0)
    __syncthreads();

    if (w == 0) {
        ABSORBA(0)
        // reduced tile into LDS as [m-within-block 128][9]
#pragma unroll
        for (int rr = 0; rr < 4; ++rr)
#pragma unroll
            for (int ct = 0; ct < 2; ++ct)
                if (n < 9)
#pragma unroll
                    for (int i = 0; i < 4; ++i)
                        sfin[(rr * 32 + ct * 16 + q * 4 + i) * 9 + n] = acc[rr][ct][i];
    }
#undef PARKA
#undef ABSORBA
    __syncthreads();

    // ---- fused normalize + coalesced store (4 row-chunks of 288 floats) ----
    const size_t obase = 8192 + ((size_t)b * 4096 + (size_t)r0 * 64 + (size_t)chalf * 32) * 9;
#pragma unroll
    for (int it = 0; it < 3; ++it) {
        const int idx = it * 512 + tid;
        if (idx < 1152) {
            const int m   = idx / 9;
            const int c9  = idx - m * 9;
            const int row = m >> 5, col = m & 31;
            const float dens = sfin[m * 9];
            const float v    = sfin[idx];
            out[obase + (size_t)row * 576 + col * 9 + c9]
                = c9 ? v * __builtin_amdgcn_rcpf(dens + 1e-6f) : dens;
        }
    }
}

extern "C" void kernel_launch(void* const* d_in, const int* in_sizes, int n_in,
                              void* d_out, int out_size, void* d_ws, size_t ws_size,
                              hipStream_t stream) {
    const float* X = (const float*)d_in[0];   // (16,1024,2) fp32
    const float* Y = (const float*)d_in[1];   // (16,1024,8) fp32
    float* out = (float*)d_out;
    (void)d_ws; (void)ws_size;

    rkhs_fused<<<dim3(512), dim3(512), 0, stream>>>(X, Y, out);
}